// Round 3
// baseline (313.451 us; speedup 1.0000x reference)
//
#include <hip/hip_runtime.h>

// Problem constants (from reference)
constexpr int S  = 4096;   // N_SAMPLES
constexpr int W  = 16;     // N_WIDTH
constexpr int NN = 193;    // N_NODES
constexpr int DD = 2;      // NDIM_IN
constexpr int SW = S * W;                  // 65536
constexpr int PHI_OFF = 3 * SW;            // 196608 (after t, dt, ddt)
constexpr int PHI_SZ  = SW * NN * DD;      // 25,296,896 per tensor
constexpr int DX_OFF  = PHI_OFF + 3 * PHI_SZ;  // 76,087,296

constexpr int ROW_F   = NN * DD;           // 386 floats per (node,dim) row
constexpr int ROW_PAD = 392;               // +2 wrap pad, rounded to /8
constexpr int R       = 8;                 // samples per block (long-stream test)
constexpr int NB      = S / R;             // 512 blocks
constexpr int CHUNK_F = W * ROW_F;         // 6176 floats per (sample, tensor)
constexpr int BLK_F4  = R * CHUNK_F / 4;   // 12352 float4 per (block, tensor)
constexpr int FULL_IT = BLK_F4 / 256;      // 48
constexpr int TAIL    = BLK_F4 - FULL_IT * 256;  // 64
constexpr int STEP_J  = 1024 % ROW_F;      // 252: j advance per 256-thread stride

// Plain clang vector type — required by __builtin_nontemporal_store.
typedef float f32x4 __attribute__((ext_vector_type(4)));

__global__ __launch_bounds__(256)
void kan_fused_kernel(const float* __restrict__ x,
                      const float* __restrict__ w,
                      float* __restrict__ out) {
    const int bx  = blockIdx.x;
    const int tid = threadIdx.x;

    // Rows for 8 samples x 3 tensors. Entries [386],[387] of each row
    // replicate [0],[1] so a 16B group starting at any even j reads 4
    // contiguous floats with no wrap branch.
    __shared__ __align__(16) float row[3][R][ROW_PAD];   // 37,632 B
    __shared__ float vals[3][R][DD][4];
    __shared__ int   nls[R][DD];

    // Phase 1a: zero all rows (incl. pads): 3*8*392/4 = 2352 float4
    {
        f32x4* rz = (f32x4*)&row[0][0][0];
        for (int idx = tid; idx < 3 * R * ROW_PAD / 4; idx += 256)
            rz[idx] = (f32x4){0.f, 0.f, 0.f, 0.f};
    }

    // Phase 1b: threads 0..15 compute the Lagrange basis, one (sample,dim) each
    if (tid < R * DD) {
        const int smp = tid >> 1;
        const int d   = tid & 1;
        float xv = x[(bx * R + smp) * DD + d];
        float xs = 192.0f * xv;                  // (N_NODES-1)*(x-xmin)/(xmax-xmin)
        float fe = floorf(xs / 3.0f);            // element index
        fe = fminf(fmaxf(fe, 0.0f), 63.0f);      // clip to [0, N_ELEMENTS-1]
        int nl = (int)(fe * 3.0f);               // left node index
        nls[smp][d] = nl;
        float xr = 2.0f * (xs - (float)nl) / 3.0f - 1.0f;   // ref coord in [-1,1]

        // Cubic Lagrange basis at nodes {-1,-1/3,1/3,1}
        float xp1 = xr + 1.0f;
        float xm1 = xr - 1.0f;
        float x2  = xr * xr;
        float x2m = x2 - (1.0f / 9.0f);          // (x+1/3)(x-1/3)
        const float c0 = 0.5625f;                // 9/16
        const float c1 = 1.6875f;                // 27/16

        vals[0][smp][d][0] = -c0 * x2m * xm1;
        vals[0][smp][d][1] =  c1 * xp1 * (xr - (1.0f / 3.0f)) * xm1;
        vals[0][smp][d][2] = -c1 * xp1 * (xr + (1.0f / 3.0f)) * xm1;
        vals[0][smp][d][3] =  c0 * xp1 * x2m;

        const float idx1 = 128.0f;               // 1/delta_x (exact, 2^7)
        vals[1][smp][d][0] = -c0 * (3.0f * x2 - 2.0f * xr - (1.0f / 9.0f)) * idx1;
        vals[1][smp][d][1] =  c1 * (3.0f * x2 - (2.0f / 3.0f) * xr - 1.0f) * idx1;
        vals[1][smp][d][2] = -c1 * (3.0f * x2 + (2.0f / 3.0f) * xr - 1.0f) * idx1;
        vals[1][smp][d][3] =  c0 * (3.0f * x2 + 2.0f * xr - (1.0f / 9.0f)) * idx1;

        const float idx2 = 16384.0f;             // 1/delta_x^2 (exact, 2^14)
        vals[2][smp][d][0] = -c0 * (6.0f * xr - 2.0f) * idx2;
        vals[2][smp][d][1] =  c1 * (6.0f * xr - (2.0f / 3.0f)) * idx2;
        vals[2][smp][d][2] = -c1 * (6.0f * xr + (2.0f / 3.0f)) * idx2;
        vals[2][smp][d][3] =  c0 * (6.0f * xr + 2.0f) * idx2;
    }

    __syncthreads();

    // Phase 2a: scatter 192 nonzero entries (3 tensors x 8 samples x 2 dims x 4)
    // plus 48 wrap-pad entries (row[..][386+d] mirrors entry d iff nl==0).
    if (tid < 192) {
        int a = tid >> 6;           // tensor 0..2
        int r = tid & 63;
        int smp = r >> 3;
        int rr  = r & 7;
        int d = rr >> 2;
        int p = rr & 3;
        row[a][smp][(nls[smp][d] + p) * DD + d] = vals[a][smp][d][p];
    } else if (tid < 240) {
        int q = tid - 192;
        int a = q >> 4;             // tensor 0..2
        int r = q & 15;
        int smp = r >> 1;
        int d   = r & 1;
        if (nls[smp][d] == 0)
            row[a][smp][ROW_F + d] = vals[a][smp][d][0];
    }

    // Phase 2b: t/dt/ddt dot products — 8 samples x 16 widths x 3 tensors = 384
    for (int t = tid; t < R * W * 3; t += 256) {
        int smp = t / 48;
        int r2  = t % 48;
        int k = r2 / 3;
        int a = r2 % 3;
        float s = 0.0f;
#pragma unroll
        for (int d = 0; d < DD; ++d) {
            int base = k * ROW_F + nls[smp][d] * DD + d;
#pragma unroll
            for (int p = 0; p < 4; ++p)
                s += w[base + p * DD] * vals[a][smp][d][p];
        }
        out[a * SW + (bx * R + smp) * W + k] = s;
    }

    if (bx == 0 && tid == 0)
        out[DX_OFF] = 0.0078125f;   // delta_x

    __syncthreads();

    // Phase 3: stream 3 contiguous 198KB spans (8 samples x 16 copies each).
    // Output float f (within the block's span of one tensor):
    //   smp = f / 6176, j = f mod 386 — both maintained incrementally
    //   (6176 = 16*386, so j never needs resync at sample boundaries).
    int j0 = tid * 4;               // <= 1020: at most two wrap subtractions
    if (j0 >= ROW_F) j0 -= ROW_F;
    if (j0 >= ROW_F) j0 -= ROW_F;

#pragma unroll
    for (int a = 0; a < 3; ++a) {
        f32x4* dst = (f32x4*)(out + PHI_OFF + (size_t)a * PHI_SZ
                                  + (size_t)bx * (R * CHUNK_F));
        const float* rowa = &row[a][0][0];
        int j = j0, fs = tid * 4, smp = 0, nn = tid;
#pragma unroll 4
        for (int it = 0; it < FULL_IT; ++it) {
            const float* rp = rowa + smp * ROW_PAD;
            float2 u = *(const float2*)&rp[j];
            float2 v = *(const float2*)&rp[j + 2];
            __builtin_nontemporal_store((f32x4){u.x, u.y, v.x, v.y}, &dst[nn]);
            nn += 256;
            fs += 1024;
            if (fs >= CHUNK_F) { fs -= CHUNK_F; smp += 1; }
            j += STEP_J;
            if (j >= ROW_F) j -= ROW_F;
        }
        if (tid < TAIL) {           // 12352 - 48*256 = 64 remaining groups
            const float* rp = rowa + smp * ROW_PAD;
            float2 u = *(const float2*)&rp[j];
            float2 v = *(const float2*)&rp[j + 2];
            __builtin_nontemporal_store((f32x4){u.x, u.y, v.x, v.y}, &dst[nn]);
        }
    }
}

extern "C" void kernel_launch(void* const* d_in, const int* in_sizes, int n_in,
                              void* d_out, int out_size, void* d_ws, size_t ws_size,
                              hipStream_t stream) {
    const float* x = (const float*)d_in[0];   // (4096, 2) fp32
    const float* w = (const float*)d_in[1];   // (16, 193, 2) fp32
    float* out = (float*)d_out;

    kan_fused_kernel<<<NB, 256, 0, stream>>>(x, w, out);
}

// Round 4
// 302.260 us; speedup vs baseline: 1.0370x; 1.0370x over previous
//
#include <hip/hip_runtime.h>

// Problem constants (from reference)
constexpr int S  = 4096;   // N_SAMPLES
constexpr int W  = 16;     // N_WIDTH
constexpr int NN = 193;    // N_NODES
constexpr int DD = 2;      // NDIM_IN
constexpr int SW = S * W;                  // 65536
constexpr int PHI_OFF = 3 * SW;            // 196608 (after t, dt, ddt)
constexpr int PHI_SZ  = SW * NN * DD;      // 25,296,896 per tensor
constexpr int DX_OFF  = PHI_OFF + 3 * PHI_SZ;  // 76,087,296

// Row length per (i,k): 193 nodes * 2 dims = 386 floats
constexpr int ROW_F    = NN * DD;          // 386
constexpr int ROW_PAD  = 392;              // 386 + 2 wrap-pad, rounded to /8
constexpr int CHUNK_F  = W * ROW_F;        // 6176 floats per (i, tensor)
constexpr int CHUNK_F4 = CHUNK_F / 4;      // 1544 float4 per (i, tensor)
constexpr int STEP_J   = (4 * 256) % ROW_F; // 252: j-advance per 256-thread stride

// Plain clang vector type (16B store emits global_store_dwordx4).
typedef float f32x4 __attribute__((ext_vector_type(4)));

__global__ __launch_bounds__(256)
void kan_fused_kernel(const float* __restrict__ x,
                      const float* __restrict__ w,
                      float* __restrict__ out) {
    const int i   = blockIdx.x;
    const int tid = threadIdx.x;

    // LDS: one padded row per output tensor (phi/dphi/ddphi). Entries
    // [386],[387] replicate [0],[1] so a 16B output group starting at any
    // even j reads 4 contiguous floats with no wrap branch.
    __shared__ __align__(16) float row[3][ROW_PAD];   // 4704 B
    __shared__ float vals[3][DD][4];
    __shared__ int   nls[DD];

    // Phase 1a: zero the rows (incl. pad): 3*392/4 = 294 float4
    {
        f32x4* rz = (f32x4*)&row[0][0];
        for (int idx = tid; idx < (3 * ROW_PAD) / 4; idx += 256)
            rz[idx] = (f32x4){0.f, 0.f, 0.f, 0.f};
    }

    // Phase 1b: threads 0,1 compute the Lagrange basis for dim d = tid
    if (tid < DD) {
        const int d = tid;
        float xv = x[i * DD + d];
        float xs = 192.0f * xv;                  // (N_NODES-1)*(x-xmin)/(xmax-xmin)
        float fe = floorf(xs / 3.0f);            // element index
        fe = fminf(fmaxf(fe, 0.0f), 63.0f);      // clip to [0, N_ELEMENTS-1]
        int nl = (int)(fe * 3.0f);               // left node index
        nls[d] = nl;
        float xr = 2.0f * (xs - (float)nl) / 3.0f - 1.0f;   // ref coord in [-1,1]

        // Cubic Lagrange basis at nodes {-1,-1/3,1/3,1}
        float xp1 = xr + 1.0f;
        float xm1 = xr - 1.0f;
        float x2  = xr * xr;
        float x2m = x2 - (1.0f / 9.0f);          // (x+1/3)(x-1/3)
        const float c0 = 0.5625f;                // 9/16
        const float c1 = 1.6875f;                // 27/16

        vals[0][d][0] = -c0 * x2m * xm1;
        vals[0][d][1] =  c1 * xp1 * (xr - (1.0f / 3.0f)) * xm1;
        vals[0][d][2] = -c1 * xp1 * (xr + (1.0f / 3.0f)) * xm1;
        vals[0][d][3] =  c0 * xp1 * x2m;

        const float idx1 = 128.0f;               // 1/delta_x (exact, 2^7)
        vals[1][d][0] = -c0 * (3.0f * x2 - 2.0f * xr - (1.0f / 9.0f)) * idx1;
        vals[1][d][1] =  c1 * (3.0f * x2 - (2.0f / 3.0f) * xr - 1.0f) * idx1;
        vals[1][d][2] = -c1 * (3.0f * x2 + (2.0f / 3.0f) * xr - 1.0f) * idx1;
        vals[1][d][3] =  c0 * (3.0f * x2 + 2.0f * xr - (1.0f / 9.0f)) * idx1;

        const float idx2 = 16384.0f;             // 1/delta_x^2 (exact, 2^14)
        vals[2][d][0] = -c0 * (6.0f * xr - 2.0f) * idx2;
        vals[2][d][1] =  c1 * (6.0f * xr - (2.0f / 3.0f)) * idx2;
        vals[2][d][2] = -c1 * (6.0f * xr + (2.0f / 3.0f)) * idx2;
        vals[2][d][3] =  c0 * (6.0f * xr + 2.0f) * idx2;
    }

    __syncthreads();

    // Phase 2a: scatter the 24 nonzero entries into the LDS rows,
    // plus the 6 wrap-pad entries (row[a][386+d] mirrors entry d: node 0, dim d).
    if (tid < 24) {
        int a = tid >> 3;           // tensor 0..2
        int r = tid & 7;
        int d = r >> 2;             // dim 0..1
        int p = r & 3;              // local basis index 0..3
        row[a][(nls[d] + p) * DD + d] = vals[a][d][p];
    } else if (tid < 30) {
        int q = tid - 24;
        int a = q >> 1;             // tensor 0..2
        int d = q & 1;              // dim 0..1
        if (nls[d] == 0)            // entry d nonzero only when left node is 0
            row[a][ROW_F + d] = vals[a][d][0];
    }

    // Phase 2b: t/dt/ddt dot products (independent of row[] — only needs vals/nls)
    if (tid < 48) {
        int k = tid / 3;            // width 0..15
        int a = tid % 3;            // tensor 0..2
        float s = 0.0f;
#pragma unroll
        for (int d = 0; d < DD; ++d) {
            int base = k * (NN * DD) + nls[d] * DD + d;
#pragma unroll
            for (int p = 0; p < 4; ++p)
                s += w[base + p * DD] * vals[a][d][p];
        }
        out[a * SW + i * W + k] = s;
    }

    if (i == 0 && tid == 0)
        out[DX_OFF] = 0.0078125f;   // delta_x

    __syncthreads();

    // Phase 3: stream the rows to global, 16 identical copies per tensor.
    // PLAIN float4 stores (global_store_dwordx4, same instruction the 6.25 TB/s
    // harness fill uses). Source float index for output float f is f % 386,
    // maintained incrementally (j += 252 mod 386). j is always even ->
    // 8B-aligned float2 LDS reads; wrap (j=384) reads pad floats [386],[387].
    int j0 = tid * 4;
    if (j0 >= 2 * ROW_F) j0 -= 2 * ROW_F;
    if (j0 >= ROW_F)     j0 -= ROW_F;

#pragma unroll
    for (int a = 0; a < 3; ++a) {
        f32x4* dst = (f32x4*)(out + PHI_OFF + (size_t)a * PHI_SZ
                                  + (size_t)i * CHUNK_F);
        int j  = j0;
        int nn = tid;
#pragma unroll
        for (int it = 0; it < 6; ++it) {        // 6*256 = 1536 of 1544
            float2 u = *(const float2*)&row[a][j];
            float2 v = *(const float2*)&row[a][j + 2];
            dst[nn] = (f32x4){u.x, u.y, v.x, v.y};
            nn += 256;
            j  += STEP_J;
            if (j >= ROW_F) j -= ROW_F;
        }
        if (tid < CHUNK_F4 - 6 * 256) {         // tail: 8 float4, same j chain
            float2 u = *(const float2*)&row[a][j];
            float2 v = *(const float2*)&row[a][j + 2];
            dst[nn] = (f32x4){u.x, u.y, v.x, v.y};
        }
    }
}

extern "C" void kernel_launch(void* const* d_in, const int* in_sizes, int n_in,
                              void* d_out, int out_size, void* d_ws, size_t ws_size,
                              hipStream_t stream) {
    const float* x = (const float*)d_in[0];   // (4096, 2) fp32
    const float* w = (const float*)d_in[1];   // (16, 193, 2) fp32
    float* out = (float*)d_out;

    kan_fused_kernel<<<S, 256, 0, stream>>>(x, w, out);
}